// Round 4
// baseline (3784.130 us; speedup 1.0000x reference)
//
#include <hip/hip_runtime.h>
#include <cstdint>
#include <cstddef>

// SNN forward, fp32-faithful to the reference's arithmetic:
//  - state (v,i) in fp32, updated with strict mul/add (__fmul_rn/__fadd_rn —
//    no FMA contraction, matching XLA/numpy elementwise semantics)
//  - conv/dot reductions: sequential ascending-k __fmaf_rn (BLAS/im2col
//    order), accumulator starts at 0, bias added AFTER the reduction
//  - conv2 k-order = (ic, kr, kc); FC j ascending; wout j ascending
//  - spike: (v_dec - 1.0f) > 0; reset: z ? 0 : v_dec; i' = 0.8f*i + inp
//  - zero-term skipping is bitwise-exact (fmaf(w,0,acc)==acc), so sparse
//    gathers/bitmaps preserve the dense rounding sequence exactly.
// One workgroup per sample, T-loop in-kernel, deterministic (no atomics).

#define TSTEPS 64
#define NB 256

__global__ __launch_bounds__(256)
void transpose_wfc(const float* __restrict__ wfc, float* __restrict__ wfcT) {
    int idx = blockIdx.x * 256 + threadIdx.x;     // [500,800] -> [800,500]
    if (idx < 500 * 800) {
        int o = idx / 800, j = idx % 800;
        wfcT[j * 500 + o] = wfc[idx];
    }
}

__global__ __launch_bounds__(512, 2)
void snn_forward(const float* __restrict__ x,      // [64,256,1,28,28]
                 const float* __restrict__ w1,     // [20,1,5,5]
                 const float* __restrict__ b1,     // [20]
                 const float* __restrict__ w2,     // [50,20,5,5]
                 const float* __restrict__ b2,     // [50]
                 const float* __restrict__ fcw,    // wfcT [800,500] (sj=500,so=1) or wfc [500,800] (sj=1,so=800)
                 long fc_sj, long fc_so,
                 const float* __restrict__ bfc,    // [500]
                 const float* __restrict__ wout,   // [10,500]
                 float* __restrict__ out)          // [64,256,10]
{
    const float CM = 0.1f;   // f32(DT*TAU_MEM_INV)
    const float CS = 0.8f;   // f32(1 - DT*TAU_SYN_INV), exact

    const int b   = blockIdx.x;
    const int tid = threadIdx.x;

    // ---- LDS (~23 KB) ----
    __shared__ float xs[28 * 36];                    // input tile, row stride 36
    __shared__ float p1[20 * 12 * 12];               // pooled L1 spikes, 0.0/1.0
    __shared__ unsigned char flag1[240];             // [20][12] row-has-spike
    __shared__ unsigned char s2s[3200];              // L2 spike map [50][8][8]
    __shared__ unsigned int  bm2[25];                // pooled-L2 bitmap (800 bits)
    __shared__ unsigned char s3[512];                // L3 spike map [500]
    __shared__ unsigned int  bm3[16];                // L3 bitmap
    __shared__ float v2s[500], i2s[500];             // L3 LIF state
    __shared__ float vos[10],  ios[10];              // output LI state

    if (tid < 500) { v2s[tid] = 0.f; i2s[tid] = 0.f; }
    if (tid < 10)  { vos[tid] = 0.f; ios[tid] = 0.f; }

    // ---- layer-1 mapping: 480 threads = 20 ch x 12 pool-rows x 2 col-halves ----
    const int l1  = (tid < 480);
    const int c   = tid / 24;
    const int sub = tid % 24;
    const int pr  = sub >> 1;          // pool row 0..11
    const int chh = sub & 1;           // column half
    const int r0  = pr * 2;
    const int c0  = chh * 12;

    float w1r[25];
    float bias1 = 0.f;
    if (l1) {
        bias1 = b1[c];
        for (int k = 0; k < 25; ++k) w1r[k] = w1[c * 25 + k];
    }
    float v0a[12], v0b[12], i0a[12], i0b[12];        // L1 state: rows r0, r0+1
    for (int j = 0; j < 12; ++j) { v0a[j] = 0.f; v0b[j] = 0.f; i0a[j] = 0.f; i0b[j] = 0.f; }

    // ---- layer-2 mapping: 400 threads = 50 oc x 8 out-rows; thread owns 8 cols ----
    const int l2  = (tid < 400);
    const int oc2 = tid >> 3;
    const int y2  = tid & 7;
    float v1r[8], i1r[8];
    for (int j = 0; j < 8; ++j) { v1r[j] = 0.f; i1r[j] = 0.f; }
    const float bias2 = l2 ? b2[oc2] : 0.f;

    for (int ts = 0; ts < TSTEPS; ++ts) {
        if (tid < 240) flag1[tid] = 0;
        const float* xp = x + ((size_t)ts * NB + b) * 784;
        for (int i = tid; i < 784; i += 512) {
            int r = i / 28, cc = i - r * 28;
            xs[r * 36 + cc] = xp[i];
        }
        __syncthreads();   // (A)

        // ========== conv1 (fma, k=(kr,kc) ascending, bias AFTER) + LIF1 + pool1 ==========
        if (l1) {
            float acc0[12], acc1[12];
            for (int j = 0; j < 12; ++j) { acc0[j] = 0.f; acc1[j] = 0.f; }
            for (int ir = 0; ir < 6; ++ir) {
                float xr[16];
                const float* rp = xs + (r0 + ir) * 36 + c0;
                for (int q = 0; q < 16; ++q) xr[q] = rp[q];
                if (ir < 5) {                      // out row r0, kr = ir
                    for (int kc = 0; kc < 5; ++kc) {
                        const float w = w1r[ir * 5 + kc];
                        for (int j = 0; j < 12; ++j)
                            acc0[j] = __fmaf_rn(w, xr[j + kc], acc0[j]);
                    }
                }
                if (ir >= 1) {                     // out row r0+1, kr = ir-1
                    for (int kc = 0; kc < 5; ++kc) {
                        const float w = w1r[(ir - 1) * 5 + kc];
                        for (int j = 0; j < 12; ++j)
                            acc1[j] = __fmaf_rn(w, xr[j + kc], acc1[j]);
                    }
                }
            }
            unsigned int zb0 = 0, zb1 = 0;
            for (int j = 0; j < 12; ++j) {
                const float inp = __fadd_rn(acc0[j], bias1);              // conv + bias
                const float vd  = __fadd_rn(v0a[j], __fmul_rn(CM, __fsub_rn(i0a[j], v0a[j])));
                const float id  = __fmul_rn(i0a[j], CS);
                const int z = (__fsub_rn(vd, 1.0f) > 0.0f);
                v0a[j] = z ? 0.f : vd;
                i0a[j] = __fadd_rn(id, inp);
                zb0 |= (unsigned)z << j;
            }
            for (int j = 0; j < 12; ++j) {
                const float inp = __fadd_rn(acc1[j], bias1);
                const float vd  = __fadd_rn(v0b[j], __fmul_rn(CM, __fsub_rn(i0b[j], v0b[j])));
                const float id  = __fmul_rn(i0b[j], CS);
                const int z = (__fsub_rn(vd, 1.0f) > 0.0f);
                v0b[j] = z ? 0.f : vd;
                i0b[j] = __fadd_rn(id, inp);
                zb1 |= (unsigned)z << j;
            }
            const unsigned int zp = zb0 | zb1;               // pool over 2 rows
            for (int jj = 0; jj < 6; ++jj)                   // pool over col pairs
                p1[(c * 12 + pr) * 12 + chh * 6 + jj] = ((zp >> (2 * jj)) & 3u) ? 1.0f : 0.0f;
            if (zp) flag1[c * 12 + pr] = 1;                  // benign same-value race
        }
        __syncthreads();   // (B)

        // ========== conv2 (fma, k=(ic,kr,kc) ascending, bias AFTER, x10 AFTER) + LIF2 ==========
        if (l2) {
            float acc[8];
            for (int xx = 0; xx < 8; ++xx) acc[xx] = 0.f;
            for (int ic = 0; ic < 20; ++ic) {
                for (int kr = 0; kr < 5; ++kr) {
                    const int py = y2 + kr;
                    if (!flag1[ic * 12 + py]) continue;       // all terms 0: fmaf(w,0,acc)==acc
                    const float* prow = p1 + (ic * 12 + py) * 12;
                    const float* wrow = w2 + ((oc2 * 20 + ic) * 5 + kr) * 5;
                    for (int kc = 0; kc < 5; ++kc) {
                        const float w = wrow[kc];
                        for (int xx = 0; xx < 8; ++xx)
                            acc[xx] = __fmaf_rn(w, prow[xx + kc], acc[xx]);
                    }
                }
            }
            unsigned long long zm = 0ull;
            for (int xx = 0; xx < 8; ++xx) {
                const float inp = __fmul_rn(10.0f, __fadd_rn(acc[xx], bias2));
                const float vd  = __fadd_rn(v1r[xx], __fmul_rn(CM, __fsub_rn(i1r[xx], v1r[xx])));
                const float id  = __fmul_rn(i1r[xx], CS);
                const int z = (__fsub_rn(vd, 1.0f) > 0.0f);
                v1r[xx] = z ? 0.f : vd;
                i1r[xx] = __fadd_rn(id, inp);
                zm |= (unsigned long long)z << (8 * xx);
            }
            ((unsigned long long*)s2s)[tid] = zm;             // row (oc2,y2)
        }
        __syncthreads();   // (C)

        // ========== pool2 -> bitmap ==========
        if (tid < 25) {
            unsigned int bits = 0;
            for (int bb = 0; bb < 32; ++bb) {
                const int u  = tid * 32 + bb;                 // fc idx, [50][4][4] C-order
                const int oc = u >> 4;
                const int py = (u >> 2) & 3;
                const int px = u & 3;
                const int base = oc * 64 + py * 16 + px * 2;
                if (s2s[base] | s2s[base + 1] | s2s[base + 8] | s2s[base + 9])
                    bits |= 1u << bb;
            }
            bm2[tid] = bits;
        }
        __syncthreads();   // (D)

        // ========== fc 800->500 (fma, j ascending, bias AFTER) + LIF3 ==========
        if (tid < 500) {
            float acc = 0.f;
            for (int w = 0; w < 25; ++w) {
                unsigned int bits = bm2[w];
                while (bits) {
                    const int bb = __builtin_ctz(bits);
                    bits &= bits - 1;
                    const long j = (long)(w * 32 + bb);       // ascending j
                    acc = __fmaf_rn(1.0f, fcw[j * fc_sj + (long)tid * fc_so], acc);
                }
            }
            const float inp = __fadd_rn(acc, bfc[tid]);
            const float vd  = __fadd_rn(v2s[tid], __fmul_rn(CM, __fsub_rn(i2s[tid], v2s[tid])));
            const float id  = __fmul_rn(i2s[tid], CS);
            const int z = (__fsub_rn(vd, 1.0f) > 0.0f);
            v2s[tid] = z ? 0.f : vd;
            i2s[tid] = __fadd_rn(id, inp);
            s3[tid] = (unsigned char)z;
        }
        __syncthreads();   // (E)

        // ========== L3 spike bitmap ==========
        if (tid < 16) {
            unsigned int bits = 0;
            for (int bb = 0; bb < 32; ++bb) {
                const int j = tid * 32 + bb;
                if (j < 500 && s3[j]) bits |= 1u << bb;
            }
            bm3[tid] = bits;
        }
        __syncthreads();   // (F)

        // ========== output LI cell (strict) ==========
        if (tid < 10) {
            float acc = 0.f;
            for (int w = 0; w < 16; ++w) {
                unsigned int bits = bm3[w];
                while (bits) {
                    const int bb = __builtin_ctz(bits);
                    bits &= bits - 1;
                    acc = __fmaf_rn(1.0f, wout[tid * 500 + (w * 32 + bb)], acc);
                }
            }
            const float vn = __fadd_rn(vos[tid], __fmul_rn(CM, __fsub_rn(ios[tid], vos[tid])));
            ios[tid] = __fadd_rn(__fmul_rn(ios[tid], CS), acc);   // i_dec + inj
            vos[tid] = vn;
            out[((size_t)ts * NB + b) * 10 + tid] = vn;
        }
        __syncthreads();   // (G)
    }
}

extern "C" void kernel_launch(void* const* d_in, const int* in_sizes, int n_in,
                              void* d_out, int out_size, void* d_ws, size_t ws_size,
                              hipStream_t stream)
{
    const float* x    = (const float*)d_in[0];
    const float* w1   = (const float*)d_in[1];
    const float* b1   = (const float*)d_in[2];
    const float* w2   = (const float*)d_in[3];
    const float* b2   = (const float*)d_in[4];
    const float* wfc  = (const float*)d_in[5];
    const float* bfc  = (const float*)d_in[6];
    const float* wout = (const float*)d_in[7];
    float* out = (float*)d_out;

    const float* fcptr = wfc;
    long sj = 1, so = 800;
    if (ws_size >= (size_t)500 * 800 * sizeof(float)) {
        float* wfcT = (float*)d_ws;
        transpose_wfc<<<(500 * 800 + 255) / 256, 256, 0, stream>>>(wfc, wfcT);
        fcptr = wfcT; sj = 500; so = 1;
    }

    snn_forward<<<NB, 512, 0, stream>>>(x, w1, b1, w2, b2, fcptr, sj, so, bfc, wout, out);
}